// Round 5
// baseline (290.432 us; speedup 1.0000x reference)
//
#include <hip/hip_runtime.h>
#include <hip/hip_bf16.h>
#include <stdint.h>

#define BATCH 8
#define CH    64
#define HH    256
#define WW    256
#define WELEM 36864       // 9*64*64 weight elems, layout [kk][o][c]

typedef __attribute__((ext_vector_type(8))) short short8;
typedef __attribute__((ext_vector_type(4))) float float4v;

__device__ __forceinline__ int swz(int byte) {
    // 128B-row XOR swizzle — proven 0-conflict (rounds 0-4) for uint4/uint2
    // staging writes and 16B fragment reads.
    return byte ^ (((byte >> 7) & 7) << 4);
}

__device__ __forceinline__ unsigned short f2bf(float v) {
    __hip_bfloat16 h = __float2bfloat16(v);
    return *reinterpret_cast<unsigned short*>(&h);
}

// ---------------- weight prep: f32 OIHW -> bf16 [kk][o][c] ----------------
__global__ __launch_bounds__(1024)
void prep_weights(const float* __restrict__ w1, const float* __restrict__ w2,
                  unsigned short* __restrict__ w1p, unsigned short* __restrict__ w2p) {
    int tid = blockIdx.x * blockDim.x + threadIdx.x;
    if (tid >= 2 * WELEM) return;
    const float* src = (tid < WELEM) ? w1 : w2;
    unsigned short* dst = (tid < WELEM) ? w1p : w2p;
    int e = (tid < WELEM) ? tid : tid - WELEM;
    int c  = e & 63;
    int o  = (e >> 6) & 63;
    int kk = e >> 12;                 // 0..8
    dst[e] = f2bf(src[o * 576 + c * 9 + kk]);
}

// ---------------- gmax prep: 3x3 maxpool of gate -> gmax image (scratch in `out`) ----------------
__global__ __launch_bounds__(1024)
void gmax_prep(const float* __restrict__ gate, float* __restrict__ gmax) {
    int p = blockIdx.x * 1024 + threadIdx.x;   // 524288 px
    int b = p >> 16, rem = p & 65535, y = rem >> 8, x = rem & 255;
    const float* gb = gate + (size_t)b * 65536;
    float m = 0.f;
    #pragma unroll
    for (int dy = -1; dy <= 1; ++dy)
        #pragma unroll
        for (int dx = -1; dx <= 1; ++dx) {
            int yy = y + dy, xx = x + dx;
            if ((unsigned)yy < HH && (unsigned)xx < WW)
                m = fmaxf(m, gb[yy * 256 + xx]);
        }
    gmax[p] = m;
}

// ---------------- transpose: x NCHW f32 -> xbf NHWC bf16 ----------------
__global__ __launch_bounds__(256)
void transpose_x(const float* __restrict__ x, unsigned short* __restrict__ xbf) {
    __shared__ unsigned short tile[64 * 66];
    const int t = threadIdx.x;
    const int bx = blockIdx.x;                 // 8192 = B(8) * H(256) * W/64(4)
    const int xt = bx & 3, y = (bx >> 2) & 255, b = bx >> 10;
    const int x0 = xt * 64;
    const float* xb = x + (size_t)b * (64 * 65536) + y * 256 + x0;
    #pragma unroll
    for (int it = 0; it < 4; ++it) {
        int idx = it * 256 + t;
        int c = idx >> 4, xi = (idx & 15) * 4;
        float4 v = *reinterpret_cast<const float4*>(xb + (size_t)c * 65536 + xi);
        ushort4 o;
        o.x = f2bf(v.x); o.y = f2bf(v.y); o.z = f2bf(v.z); o.w = f2bf(v.w);
        *reinterpret_cast<ushort4*>(&tile[c * 66 + xi]) = o;
    }
    __syncthreads();
    unsigned short* ob = xbf + ((size_t)(b * 65536 + y * 256 + x0)) * 64;
    #pragma unroll
    for (int it = 0; it < 2; ++it) {
        int idx = it * 256 + t;
        int pix = idx >> 3, cg = idx & 7;
        unsigned short tmp[8];
        #pragma unroll
        for (int j = 0; j < 8; ++j) tmp[j] = tile[(cg * 8 + j) * 66 + pix];
        *reinterpret_cast<uint4*>(ob + (size_t)pix * 64 + cg * 8) = *reinterpret_cast<uint4*>(tmp);
    }
}

// ---------------- conv1: xbf -> h; 1024 thr, 16 waves, tile 32x32, m4n4 ----------------
__global__ __launch_bounds__(1024, 2)
void conv1_kernel(const unsigned short* __restrict__ xbf, const float* __restrict__ gmaxg,
                  const unsigned short* __restrict__ wp,
                  const float* __restrict__ scale1, const float* __restrict__ bias1,
                  unsigned short* __restrict__ h) {
    enum { T1W = 32, T1H = 32, P1W = 34, P1H = 34, N1 = P1W * P1H };  // N1=1156
    __shared__ __align__(16) unsigned short patch[N1 * 64];   // 147968 B
    __shared__ __align__(16) unsigned short wlds[4096];       // 8192 B (one kk chunk)

    const int tid = threadIdx.x;
    const int bx  = blockIdx.x;                // 512 = 8 tx * 8 ty * 8 b
    const int txi = bx & 7, tyi = (bx >> 3) & 7, b = bx >> 6;
    const int x0 = txi * T1W, y0 = tyi * T1H;

    char* pb = (char*)patch;
    char* wb = (char*)wlds;

    // stage x patch (NHWC bf16), coalesced uint4
    const unsigned short* hbase = xbf + (size_t)b * (65536 * 64);
    #pragma unroll
    for (int i = 0; i < 10; ++i) {
        int ch = tid + i * 1024;               // < 9248
        if (ch < N1 * 8) {
            int row = ch / (P1W * 8);
            int rem = ch - row * (P1W * 8);
            int px = rem >> 3, cc = rem & 7;
            int y = y0 - 1 + row, xg = x0 - 1 + px;
            uint4 v = make_uint4(0u, 0u, 0u, 0u);
            if ((unsigned)y < HH && (unsigned)xg < WW)
                v = *reinterpret_cast<const uint4*>(hbase + ((size_t)(y * 256 + xg) * 64 + cc * 8));
            *reinterpret_cast<uint4*>(pb + swz((row * P1W + px) * 128 + cc * 16)) = v;
        }
    }
    // stage weight chunk kk=0 (8192B, uint2/thread), prefetch chunk 1 to regs
    {
        uint2 c0 = *reinterpret_cast<const uint2*>((const char*)wp + tid * 8);
        *reinterpret_cast<uint2*>(wb + swz(tid * 8)) = c0;
    }
    uint2 pf = *reinterpret_cast<const uint2*>((const char*)wp + 8192 + tid * 8);
    __syncthreads();

    const int w = tid >> 6, l = tid & 63;      // 16 waves; wave w -> rows 2w, 2w+1
    const int l15 = l & 15, lq = l >> 4;

    float4v acc[4][4];                         // [m: rowoff*2+half][nt: oc-frag]
    #pragma unroll
    for (int m = 0; m < 4; ++m)
        #pragma unroll
        for (int n = 0; n < 4; ++n)
            acc[m][n] = (float4v){0.f, 0.f, 0.f, 0.f};

    for (int kk = 0; kk < 9; ++kk) {
        const int ky = kk / 3, kx = kk - ky * 3;
        #pragma unroll
        for (int kc = 0; kc < 2; ++kc) {
            const int kbyte = kc * 64 + lq * 16;
            short8 a[4];
            #pragma unroll
            for (int m = 0; m < 4; ++m)
                a[m] = *reinterpret_cast<const short8*>(
                    pb + swz(((2 * w + (m >> 1) + ky) * P1W + (m & 1) * 16 + l15 + kx) * 128 + kbyte));
            #pragma unroll
            for (int nt = 0; nt < 4; ++nt) {
                short8 bf = *reinterpret_cast<const short8*>(
                    wb + swz((nt * 16 + l15) * 128 + kbyte));
                #pragma unroll
                for (int m = 0; m < 4; ++m)
                    acc[m][nt] = __builtin_amdgcn_mfma_f32_16x16x32_bf16(a[m], bf, acc[m][nt], 0, 0, 0);
            }
        }
        if (kk < 8) {
            __syncthreads();                   // all reads of current chunk done
            *reinterpret_cast<uint2*>(wb + swz(tid * 8)) = pf;
            if (kk < 7)
                pf = *reinterpret_cast<const uint2*>((const char*)wp + (kk + 2) * 8192 + tid * 8);
            __syncthreads();                   // next chunk visible
        }
    }

    // epilogue: BN1 + ReLU + *gmax(global, precomputed), store NHWC bf16
    float s1v[4], b1v[4];
    #pragma unroll
    for (int nt = 0; nt < 4; ++nt) {
        s1v[nt] = scale1[nt * 16 + l15];
        b1v[nt] = bias1[nt * 16 + l15];
    }
    const float* gm = gmaxg + (size_t)b * 65536;
    #pragma unroll
    for (int m = 0; m < 4; ++m) {
        const int yy = y0 + 2 * w + (m >> 1);
        unsigned short* hb = h + ((size_t)b * 65536 + (size_t)yy * 256) * 64;
        #pragma unroll
        for (int r = 0; r < 4; ++r) {
            int xx = x0 + (m & 1) * 16 + lq * 4 + r;
            float g = gm[yy * 256 + xx];
            #pragma unroll
            for (int nt = 0; nt < 4; ++nt) {
                float v = acc[m][nt][r] * s1v[nt] + b1v[nt];
                v = fmaxf(v, 0.f) * g;
                hb[(size_t)xx * 64 + nt * 16 + l15] = f2bf(v);
            }
        }
    }
}

// ---------------- conv1 fallback (ws too small): stage from x NCHW f32 ----------------
__global__ __launch_bounds__(1024, 2)
void conv1_fallback(const float* __restrict__ x, const float* __restrict__ gmaxg,
                    const unsigned short* __restrict__ wp,
                    const float* __restrict__ scale1, const float* __restrict__ bias1,
                    unsigned short* __restrict__ h) {
    enum { T1W = 32, T1H = 32, P1W = 34, P1H = 34, N1 = P1W * P1H };
    __shared__ __align__(16) unsigned short patch[N1 * 64];
    __shared__ __align__(16) unsigned short wlds[4096];

    const int tid = threadIdx.x;
    const int bx  = blockIdx.x;
    const int txi = bx & 7, tyi = (bx >> 3) & 7, b = bx >> 6;
    const int x0 = txi * T1W, y0 = tyi * T1H;

    char* pb = (char*)patch;
    char* wb = (char*)wlds;

    const float* xb = x + (size_t)b * (64 * 65536);
    for (int e = tid; e < N1 * 64; e += 1024) {
        int c  = e / N1;
        int rp = e - c * N1;
        int row = rp / P1W;
        int px  = rp - row * P1W;
        int y = y0 - 1 + row, xg = x0 - 1 + px;
        float v = 0.f;
        if ((unsigned)y < HH && (unsigned)xg < WW)
            v = xb[(size_t)c * 65536 + y * 256 + xg];
        *reinterpret_cast<unsigned short*>(pb + swz(rp * 128 + c * 2)) = f2bf(v);
    }
    {
        uint2 c0 = *reinterpret_cast<const uint2*>((const char*)wp + tid * 8);
        *reinterpret_cast<uint2*>(wb + swz(tid * 8)) = c0;
    }
    uint2 pf = *reinterpret_cast<const uint2*>((const char*)wp + 8192 + tid * 8);
    __syncthreads();

    const int w = tid >> 6, l = tid & 63;
    const int l15 = l & 15, lq = l >> 4;

    float4v acc[4][4];
    #pragma unroll
    for (int m = 0; m < 4; ++m)
        #pragma unroll
        for (int n = 0; n < 4; ++n)
            acc[m][n] = (float4v){0.f, 0.f, 0.f, 0.f};

    for (int kk = 0; kk < 9; ++kk) {
        const int ky = kk / 3, kx = kk - ky * 3;
        #pragma unroll
        for (int kc = 0; kc < 2; ++kc) {
            const int kbyte = kc * 64 + lq * 16;
            short8 a[4];
            #pragma unroll
            for (int m = 0; m < 4; ++m)
                a[m] = *reinterpret_cast<const short8*>(
                    pb + swz(((2 * w + (m >> 1) + ky) * P1W + (m & 1) * 16 + l15 + kx) * 128 + kbyte));
            #pragma unroll
            for (int nt = 0; nt < 4; ++nt) {
                short8 bf = *reinterpret_cast<const short8*>(
                    wb + swz((nt * 16 + l15) * 128 + kbyte));
                #pragma unroll
                for (int m = 0; m < 4; ++m)
                    acc[m][nt] = __builtin_amdgcn_mfma_f32_16x16x32_bf16(a[m], bf, acc[m][nt], 0, 0, 0);
            }
        }
        if (kk < 8) {
            __syncthreads();
            *reinterpret_cast<uint2*>(wb + swz(tid * 8)) = pf;
            if (kk < 7)
                pf = *reinterpret_cast<const uint2*>((const char*)wp + (kk + 2) * 8192 + tid * 8);
            __syncthreads();
        }
    }

    float s1v[4], b1v[4];
    #pragma unroll
    for (int nt = 0; nt < 4; ++nt) {
        s1v[nt] = scale1[nt * 16 + l15];
        b1v[nt] = bias1[nt * 16 + l15];
    }
    const float* gm = gmaxg + (size_t)b * 65536;
    #pragma unroll
    for (int m = 0; m < 4; ++m) {
        const int yy = y0 + 2 * w + (m >> 1);
        unsigned short* hb = h + ((size_t)b * 65536 + (size_t)yy * 256) * 64;
        #pragma unroll
        for (int r = 0; r < 4; ++r) {
            int xx = x0 + (m & 1) * 16 + lq * 4 + r;
            float g = gm[yy * 256 + xx];
            #pragma unroll
            for (int nt = 0; nt < 4; ++nt) {
                float v = acc[m][nt][r] * s1v[nt] + b1v[nt];
                v = fmaxf(v, 0.f) * g;
                hb[(size_t)xx * 64 + nt * 16 + l15] = f2bf(v);
            }
        }
    }
}

// ---------------- conv2: h -> out + residual; 1024 thr, 16 waves, tile 64x16, m4n4 ----------------
__global__ __launch_bounds__(1024, 2)
void conv2_kernel(const unsigned short* __restrict__ h, const float* __restrict__ x,
                  const float* __restrict__ gate, const unsigned short* __restrict__ wp,
                  const float* __restrict__ scale2, const float* __restrict__ bias2,
                  float* __restrict__ out) {
    enum { T2W = 64, T2H = 16, P2W = 66, P2H = 18, N2 = P2W * P2H };  // N2=1188
    __shared__ __align__(16) unsigned short patch[N2 * 64];   // 152064 B
    __shared__ __align__(16) unsigned short wlds[4096];       // 8192 B

    const int tid = threadIdx.x;
    const int bx  = blockIdx.x;                // 512 = 4 tx * 16 ty * 8 b
    const int txi = bx & 3, tyi = (bx >> 2) & 15, b = bx >> 6;
    const int x0 = txi * T2W, y0 = tyi * T2H;

    char* pb = (char*)patch;
    char* wb = (char*)wlds;

    const unsigned short* hbase = h + (size_t)b * (65536 * 64);
    #pragma unroll
    for (int i = 0; i < 10; ++i) {
        int ch = tid + i * 1024;               // < 9504
        if (ch < N2 * 8) {
            int row = ch / (P2W * 8);
            int rem = ch - row * (P2W * 8);
            int px = rem >> 3, cc = rem & 7;
            int y = y0 - 1 + row, xg = x0 - 1 + px;
            uint4 v = make_uint4(0u, 0u, 0u, 0u);
            if ((unsigned)y < HH && (unsigned)xg < WW)
                v = *reinterpret_cast<const uint4*>(hbase + ((size_t)(y * 256 + xg) * 64 + cc * 8));
            *reinterpret_cast<uint4*>(pb + swz((row * P2W + px) * 128 + cc * 16)) = v;
        }
    }
    {
        uint2 c0 = *reinterpret_cast<const uint2*>((const char*)wp + tid * 8);
        *reinterpret_cast<uint2*>(wb + swz(tid * 8)) = c0;
    }
    uint2 pf = *reinterpret_cast<const uint2*>((const char*)wp + 8192 + tid * 8);
    __syncthreads();

    const int w = tid >> 6, l = tid & 63;      // 16 waves; wave w -> row w
    const int l15 = l & 15, lq = l >> 4;

    float4v acc[4][4];                         // [mt: oc-frag][nt: px-frag]
    #pragma unroll
    for (int m = 0; m < 4; ++m)
        #pragma unroll
        for (int n = 0; n < 4; ++n)
            acc[m][n] = (float4v){0.f, 0.f, 0.f, 0.f};

    for (int kk = 0; kk < 9; ++kk) {
        const int ky = kk / 3, kx = kk - ky * 3;
        #pragma unroll
        for (int kc = 0; kc < 2; ++kc) {
            const int kbyte = kc * 64 + lq * 16;
            short8 bp[4];
            #pragma unroll
            for (int nt = 0; nt < 4; ++nt)
                bp[nt] = *reinterpret_cast<const short8*>(
                    pb + swz(((w + ky) * P2W + nt * 16 + l15 + kx) * 128 + kbyte));
            #pragma unroll
            for (int mt = 0; mt < 4; ++mt) {
                short8 aw = *reinterpret_cast<const short8*>(
                    wb + swz((mt * 16 + l15) * 128 + kbyte));
                #pragma unroll
                for (int nt = 0; nt < 4; ++nt)
                    acc[mt][nt] = __builtin_amdgcn_mfma_f32_16x16x32_bf16(aw, bp[nt], acc[mt][nt], 0, 0, 0);
            }
        }
        if (kk < 8) {
            __syncthreads();
            *reinterpret_cast<uint2*>(wb + swz(tid * 8)) = pf;
            if (kk < 7)
                pf = *reinterpret_cast<const uint2*>((const char*)wp + (kk + 2) * 8192 + tid * 8);
            __syncthreads();
        }
    }

    // epilogue: BN2 + *gate + residual + ReLU, store NCHW f32 (l15 = px -> coalesced)
    const int yy = y0 + w;
    const float* gr = gate + (size_t)b * 65536 + yy * 256 + x0;
    float g[4];
    #pragma unroll
    for (int nt = 0; nt < 4; ++nt) g[nt] = gr[nt * 16 + l15];
    #pragma unroll
    for (int mt = 0; mt < 4; ++mt)
        #pragma unroll
        for (int r = 0; r < 4; ++r) {
            int oc = mt * 16 + lq * 4 + r;
            float sc = scale2[oc], bi = bias2[oc];
            size_t base = ((size_t)(b * 64 + oc) * 256 + yy) * 256 + x0;
            #pragma unroll
            for (int nt = 0; nt < 4; ++nt) {
                int px = nt * 16 + l15;
                float v = acc[mt][nt][r] * sc + bi;
                v *= g[nt];
                v += x[base + px];
                out[base + px] = fmaxf(v, 0.f);
            }
        }
}

extern "C" void kernel_launch(void* const* d_in, const int* in_sizes, int n_in,
                              void* d_out, int out_size, void* d_ws, size_t ws_size,
                              hipStream_t stream) {
    const float* x      = (const float*)d_in[0];
    const float* gate   = (const float*)d_in[1];
    const float* w1     = (const float*)d_in[2];
    const float* scale1 = (const float*)d_in[3];
    const float* bias1  = (const float*)d_in[4];
    const float* w2     = (const float*)d_in[5];
    const float* scale2 = (const float*)d_in[6];
    const float* bias2  = (const float*)d_in[7];
    float* out = (float*)d_out;

    char* ws = (char*)d_ws;
    const size_t HBYTES = 67108864;            // 64 MiB NHWC bf16 h
    const size_t NEED_BIG = 2 * HBYTES + 2 * 73728;

    // gmax (3x3 maxpool of gate) lives in `out` as scratch: consumed only by conv1,
    // and conv2 (which fully overwrites out) runs strictly after conv1 on the stream.
    float* gmaxbuf = out;

    if (ws_size >= NEED_BIG) {
        unsigned short* hbuf = (unsigned short*)ws;
        unsigned short* xbf  = (unsigned short*)(ws + HBYTES);
        unsigned short* w1p  = (unsigned short*)(ws + 2 * HBYTES);
        unsigned short* w2p  = (unsigned short*)(ws + 2 * HBYTES + 73728);
        prep_weights<<<72, 1024, 0, stream>>>(w1, w2, w1p, w2p);
        gmax_prep<<<512, 1024, 0, stream>>>(gate, gmaxbuf);
        transpose_x<<<8192, 256, 0, stream>>>(x, xbf);
        conv1_kernel<<<512, 1024, 0, stream>>>(xbf, gmaxbuf, w1p, scale1, bias1, hbuf);
        conv2_kernel<<<512, 1024, 0, stream>>>(hbuf, x, gate, w2p, scale2, bias2, out);
    } else {
        unsigned short* hbuf = (unsigned short*)ws;
        unsigned short* w1p  = (unsigned short*)(ws + HBYTES);
        unsigned short* w2p  = (unsigned short*)(ws + HBYTES + 73728);
        prep_weights<<<72, 1024, 0, stream>>>(w1, w2, w1p, w2p);
        gmax_prep<<<512, 1024, 0, stream>>>(gate, gmaxbuf);
        conv1_fallback<<<512, 1024, 0, stream>>>(x, gmaxbuf, w1p, scale1, bias1, hbuf);
        conv2_kernel<<<512, 1024, 0, stream>>>(hbuf, x, gate, w2p, scale2, bias2, out);
    }
}